// Round 7
// baseline (2970.647 us; speedup 1.0000x reference)
//
#include <hip/hip_runtime.h>
#include <hip/hip_fp16.h>

#define D 128
#define NCHUNK 8        // feature chunks == XCD count; 16 feats (32 B fp16) per chunk
#define N_ITER 20
#define ROWS_PER_WAVE 4

// ---------------- mask dtype detection ----------------
__global__ void k_detect(const unsigned char* __restrict__ m, int nbytes, int* flag) {
    __shared__ int s;
    if (threadIdx.x == 0) s = 0;
    __syncthreads();
    int c = 0;
    for (int i = threadIdx.x; i < nbytes; i += 256)
        if ((i & 3) && m[i]) c++;
    atomicAdd(&s, c);
    __syncthreads();
    if (threadIdx.x == 0) *flag = (s > 0) ? 1 : 0;
}

__global__ void k_mask(const void* __restrict__ mraw, const int* __restrict__ flag,
                       unsigned char* __restrict__ m8, int n) {
    int i = blockIdx.x * 256 + threadIdx.x;
    if (i >= n) return;
    unsigned char v;
    if (*flag) {
        v = ((const unsigned char*)mraw)[i] != 0;
    } else {
        v = ((const int*)mraw)[i] != 0;
    }
    m8[i] = v;
}

// ---------------- degree counting ----------------
__global__ void k_deg(const int* __restrict__ row, const int* __restrict__ col, int E,
                      const unsigned char* __restrict__ m8,
                      int* __restrict__ deg, int* __restrict__ rdeg) {
    int e = blockIdx.x * 256 + threadIdx.x;
    if (e >= E) return;
    atomicAdd(&deg[col[e]], 1);
    int r = row[e];
    if (!m8[r]) atomicAdd(&rdeg[r], 1);
}

__global__ void k_dis(const int* __restrict__ deg, float* __restrict__ dis, int n) {
    int i = blockIdx.x * 256 + threadIdx.x;
    if (i >= n) return;
    int d = deg[i];
    dis[i] = (d > 0) ? rsqrtf((float)d) : 0.f;
}

// ---------------- exclusive scan of rdeg -> row_off ----------------
__global__ void k_scan1(const int* __restrict__ rdeg, int* __restrict__ csum, int n) {
    __shared__ int sh[256];
    int base = blockIdx.x * 2048;
    int t = threadIdx.x;
    int s = 0;
    for (int j = 0; j < 8; j++) {
        int i = base + t * 8 + j;
        if (i < n) s += rdeg[i];
    }
    sh[t] = s;
    __syncthreads();
    for (int o = 128; o > 0; o >>= 1) {
        if (t < o) sh[t] += sh[t + o];
        __syncthreads();
    }
    if (t == 0) csum[blockIdx.x] = sh[0];
}

__global__ void k_scan2(int* __restrict__ csum, int nch, int* __restrict__ row_off, int n) {
    if (threadIdx.x == 0) {
        int acc = 0;
        for (int i = 0; i < nch; i++) { int v = csum[i]; csum[i] = acc; acc += v; }
        row_off[n] = acc;
    }
}

__global__ void k_scan3(const int* __restrict__ rdeg, const int* __restrict__ csum,
                        int* __restrict__ row_off, int n) {
    __shared__ int sh[256];
    int base = blockIdx.x * 2048;
    int t = threadIdx.x;
    int loc[8];
    int s = 0;
    for (int j = 0; j < 8; j++) {
        int i = base + t * 8 + j;
        int v = (i < n) ? rdeg[i] : 0;
        loc[j] = s;
        s += v;
    }
    sh[t] = s;
    __syncthreads();
    for (int o = 1; o < 256; o <<= 1) {
        int v = (t >= o) ? sh[t - o] : 0;
        __syncthreads();
        sh[t] += v;
        __syncthreads();
    }
    int toff = csum[blockIdx.x] + ((t > 0) ? sh[t - 1] : 0);
    for (int j = 0; j < 8; j++) {
        int i = base + t * 8 + j;
        if (i < n) row_off[i] = toff + loc[j];
    }
}

// ---------------- scatter (filtered) edges into CSR: col only ----------------
__global__ void k_scatter(const int* __restrict__ row, const int* __restrict__ col, int E,
                          const unsigned char* __restrict__ m8,
                          const int* __restrict__ row_off, int* __restrict__ cursor,
                          int* __restrict__ col_s) {
    int e = blockIdx.x * 256 + threadIdx.x;
    if (e >= E) return;
    int r = row[e];
    if (m8[r]) return;
    int p = row_off[r] + atomicAdd(&cursor[r], 1);
    col_s[p] = col[e];
}

// ---------------- compact unmasked rows ----------------
__global__ void k_compact(const unsigned char* __restrict__ m8, int n,
                          int* __restrict__ rows_c, int* __restrict__ cnt) {
    int i = blockIdx.x * 256 + threadIdx.x;
    if (i >= n) return;
    if (!m8[i]) {
        int p = atomicAdd(cnt, 1);
        rows_c[p] = i;
    }
}

// ---------------- init: chunk-major u0 = mask ? dis*x : 0; masked rows of d_out = x --------
// u layout (half2 units): u[chunk*N*8 + node*8 + f], chunk in [0,8), f in [0,8)
__global__ void k_init(const float* __restrict__ x, const unsigned char* __restrict__ m8,
                       const float* __restrict__ dis,
                       __half2* __restrict__ uA, __half2* __restrict__ uB,
                       float* __restrict__ out, int N) {
    int tid = blockIdx.x * 256 + threadIdx.x;   // one thread per (node, half2 pair)
    if (tid >= N * 64) return;
    int node = tid >> 6;
    int q = tid & 63;            // q-th half2 of the row
    int chunk = q >> 3, f = q & 7;
    __half2 u;
    if (m8[node]) {
        float2 v = ((const float2*)x)[tid];
        ((float2*)out)[tid] = v;                 // masked rows of d_out = x exactly
        float d = dis[node];
        u = __floats2half2_rn(d * v.x, d * v.y);
    } else {
        u = __floats2half2_rn(0.f, 0.f);
    }
    size_t p = (size_t)chunk * N * 8 + (size_t)node * 8 + f;
    uA[p] = u;
    uB[p] = u;
}

// ---------------- propagation: XCD-chunked, 4 rows per wave ----------------
// chunk = blockIdx % 8 -> XCD (round-robin dispatch); chunk-k features (3.2 MB) are
// written and read only by XCD k => XCD-local L2 serves the random gathers.
// lane = 8*sub + f: 8 edge slots x 8 half2 feature lanes. col_s read normally (L3).
// u_new[r] = dis[r]^2 * sum_e u[col_e]; final: out[r] = dis[r] * sum_e u[col_e] (fp32).
template <bool FINAL>
__global__ __launch_bounds__(256) void k_prop(const __half2* __restrict__ src,
                                              void* __restrict__ dst,
                                              const int* __restrict__ rows_c,
                                              const int* __restrict__ cnt_p,
                                              const int* __restrict__ row_off,
                                              const int* __restrict__ col_s,
                                              const float* __restrict__ dis, int N) {
    int chunk = blockIdx.x & 7;
    int wgrp = (blockIdx.x >> 3) * (4 * ROWS_PER_WAVE) + (threadIdx.x >> 6) * ROWS_PER_WAVE;
    int lane = threadIdx.x & 63;
    int cnt = *cnt_p;
    if (wgrp >= cnt) return;

    int sub = lane >> 3;   // edge slot 0..7
    int f = lane & 7;      // half2 slot within the 16-feature chunk
    const __half2* cb = src + (size_t)chunk * (N * 8) + f;  // node stride = 8 half2

    for (int k = 0; k < ROWS_PER_WAVE; k++) {
        int wid = wgrp + k;
        if (wid >= cnt) break;
        int r = __builtin_amdgcn_readfirstlane(rows_c[wid]);
        int beg = __builtin_amdgcn_readfirstlane(row_off[r]);
        int end = __builtin_amdgcn_readfirstlane(row_off[r + 1]);

        float ax = 0.f, ay = 0.f, bx = 0.f, by = 0.f;
        int e = beg;
        for (; e + 16 <= end; e += 16) {
            int c0 = col_s[e + sub];
            int c1 = col_s[e + 8 + sub];
            float2 v0 = __half22float2(cb[(size_t)c0 * 8]);
            float2 v1 = __half22float2(cb[(size_t)c1 * 8]);
            ax += v0.x; ay += v0.y;
            bx += v1.x; by += v1.y;
        }
        for (; e + 8 <= end; e += 8) {
            int c0 = col_s[e + sub];
            float2 v0 = __half22float2(cb[(size_t)c0 * 8]);
            ax += v0.x; ay += v0.y;
        }
        if (e + sub < end) {
            int c0 = col_s[e + sub];
            float2 v0 = __half22float2(cb[(size_t)c0 * 8]);
            ax += v0.x; ay += v0.y;
        }
        ax += bx; ay += by;
        // reduce across the 8 edge slots (lane strides 8,16,32)
        ax += __shfl_xor(ax, 8, 64);  ay += __shfl_xor(ay, 8, 64);
        ax += __shfl_xor(ax, 16, 64); ay += __shfl_xor(ay, 16, 64);
        ax += __shfl_xor(ax, 32, 64); ay += __shfl_xor(ay, 32, 64);

        if (lane < 8) {
            float d = dis[r];
            if (FINAL) {
                // d_out row-major: float2 index r*64 + chunk*8 + f
                ((float2*)dst)[(size_t)r * 64 + chunk * 8 + f] = make_float2(d * ax, d * ay);
            } else {
                float s2 = d * d;
                __half2 hv = __floats2half2_rn(s2 * ax, s2 * ay);
                unsigned int bits;
                __builtin_memcpy(&bits, &hv, 4);
                ((unsigned int*)dst)[(size_t)chunk * (N * 8) + (size_t)r * 8 + f] = bits;
            }
        }
    }
}

extern "C" void kernel_launch(void* const* d_in, const int* in_sizes, int n_in,
                              void* d_out, int out_size, void* d_ws, size_t ws_size,
                              hipStream_t stream) {
    const float* x = (const float*)d_in[0];
    const int* ei = (const int*)d_in[1];
    const void* mraw = d_in[2];

    const int N = in_sizes[0] / D;     // 100000
    const int E = in_sizes[1] / 2;     // 3200000
    const int* row = ei;
    const int* col = ei + E;

    char* ws = (char*)d_ws;
    size_t off = 0;
    __half2* uA = (__half2*)(ws + off);     off += (size_t)N * D * 2;   // chunk-major half feats
    __half2* uB = (__half2*)(ws + off);     off += (size_t)N * D * 2;
    int* col_s = (int*)(ws + off);          off += (size_t)E * 4;       // CSR cols (filtered)
    int* row_off = (int*)(ws + off);        off += (size_t)(N + 1) * 4;
    int* zblock = (int*)(ws + off);         off += (size_t)(3 * N + 1) * 4; // deg|rdeg|cursor|cnt
    int* deg = zblock;
    int* rdeg = zblock + N;
    int* cursor = zblock + 2 * N;
    int* cnt = zblock + 3 * N;
    float* dis = (float*)(ws + off);        off += (size_t)N * 4;
    int* rows_c = (int*)(ws + off);         off += (size_t)N * 4;
    unsigned char* m8 = (unsigned char*)(ws + off); off += (size_t)N;
    off = (off + 255) & ~(size_t)255;
    int* csum = (int*)(ws + off);           off += 256 * 4;
    int* flag = (int*)(ws + off);           off += 4;

    (void)hipMemsetAsync(zblock, 0, (size_t)(3 * N + 1) * 4, stream);

    k_detect<<<1, 256, 0, stream>>>((const unsigned char*)mraw, N, flag);
    k_mask<<<(N + 255) / 256, 256, 0, stream>>>(mraw, flag, m8, N);
    k_deg<<<(E + 255) / 256, 256, 0, stream>>>(row, col, E, m8, deg, rdeg);
    k_dis<<<(N + 255) / 256, 256, 0, stream>>>(deg, dis, N);

    int nch = (N + 2047) / 2048;
    k_scan1<<<nch, 256, 0, stream>>>(rdeg, csum, N);
    k_scan2<<<1, 64, 0, stream>>>(csum, nch, row_off, N);
    k_scan3<<<nch, 256, 0, stream>>>(rdeg, csum, row_off, N);

    k_scatter<<<(E + 255) / 256, 256, 0, stream>>>(row, col, E, m8, row_off, cursor, col_s);
    k_compact<<<(N + 255) / 256, 256, 0, stream>>>(m8, N, rows_c, cnt);

    k_init<<<(N * 64 + 255) / 256, 256, 0, stream>>>(x, m8, dis, uA, uB, (float*)d_out, N);

    // 19 half iterations ping-pong, then final fp32 iteration into d_out.
    // grid: 8 chunks x ceil(N/16) row-groups; blockIdx%8 -> chunk -> XCD (round-robin).
    // Each block: 4 waves x ROWS_PER_WAVE rows = 16 rows of one chunk.
    int blocks = 8 * ((N + 4 * ROWS_PER_WAVE - 1) / (4 * ROWS_PER_WAVE));
    __half2* src = uA;
    __half2* dst = uB;
    for (int it = 0; it < N_ITER - 1; it++) {
        k_prop<false><<<blocks, 256, 0, stream>>>(src, dst, rows_c, cnt, row_off, col_s, dis, N);
        __half2* t = src; src = dst; dst = t;
    }
    k_prop<true><<<blocks, 256, 0, stream>>>(src, d_out, rows_c, cnt, row_off, col_s, dis, N);
}

// Round 8
// 1354.360 us; speedup vs baseline: 2.1934x; 2.1934x over previous
//
#include <hip/hip_runtime.h>
#include <hip/hip_fp16.h>

#define D 128
#define N_ITER 20

// ---------------- mask dtype detection ----------------
__global__ void k_detect(const unsigned char* __restrict__ m, int nbytes, int* flag) {
    __shared__ int s;
    if (threadIdx.x == 0) s = 0;
    __syncthreads();
    int c = 0;
    for (int i = threadIdx.x; i < nbytes; i += 256)
        if ((i & 3) && m[i]) c++;
    atomicAdd(&s, c);
    __syncthreads();
    if (threadIdx.x == 0) *flag = (s > 0) ? 1 : 0;
}

__global__ void k_mask(const void* __restrict__ mraw, const int* __restrict__ flag,
                       unsigned char* __restrict__ m8, int n) {
    int i = blockIdx.x * 256 + threadIdx.x;
    if (i >= n) return;
    unsigned char v;
    if (*flag) {
        v = ((const unsigned char*)mraw)[i] != 0;
    } else {
        v = ((const int*)mraw)[i] != 0;
    }
    m8[i] = v;
}

// ---------------- degree counting ----------------
__global__ void k_deg(const int* __restrict__ row, const int* __restrict__ col, int E,
                      const unsigned char* __restrict__ m8,
                      int* __restrict__ deg, int* __restrict__ rdeg) {
    int e = blockIdx.x * 256 + threadIdx.x;
    if (e >= E) return;
    atomicAdd(&deg[col[e]], 1);
    int r = row[e];
    if (!m8[r]) atomicAdd(&rdeg[r], 1);
}

__global__ void k_dis(const int* __restrict__ deg, float* __restrict__ dis, int n) {
    int i = blockIdx.x * 256 + threadIdx.x;
    if (i >= n) return;
    int d = deg[i];
    dis[i] = (d > 0) ? rsqrtf((float)d) : 0.f;
}

// ---------------- exclusive scan of rdeg -> row_off ----------------
__global__ void k_scan1(const int* __restrict__ rdeg, int* __restrict__ csum, int n) {
    __shared__ int sh[256];
    int base = blockIdx.x * 2048;
    int t = threadIdx.x;
    int s = 0;
    for (int j = 0; j < 8; j++) {
        int i = base + t * 8 + j;
        if (i < n) s += rdeg[i];
    }
    sh[t] = s;
    __syncthreads();
    for (int o = 128; o > 0; o >>= 1) {
        if (t < o) sh[t] += sh[t + o];
        __syncthreads();
    }
    if (t == 0) csum[blockIdx.x] = sh[0];
}

__global__ void k_scan2(int* __restrict__ csum, int nch, int* __restrict__ row_off, int n) {
    if (threadIdx.x == 0) {
        int acc = 0;
        for (int i = 0; i < nch; i++) { int v = csum[i]; csum[i] = acc; acc += v; }
        row_off[n] = acc;
    }
}

__global__ void k_scan3(const int* __restrict__ rdeg, const int* __restrict__ csum,
                        int* __restrict__ row_off, int n) {
    __shared__ int sh[256];
    int base = blockIdx.x * 2048;
    int t = threadIdx.x;
    int loc[8];
    int s = 0;
    for (int j = 0; j < 8; j++) {
        int i = base + t * 8 + j;
        int v = (i < n) ? rdeg[i] : 0;
        loc[j] = s;
        s += v;
    }
    sh[t] = s;
    __syncthreads();
    for (int o = 1; o < 256; o <<= 1) {
        int v = (t >= o) ? sh[t - o] : 0;
        __syncthreads();
        sh[t] += v;
        __syncthreads();
    }
    int toff = csum[blockIdx.x] + ((t > 0) ? sh[t - 1] : 0);
    for (int j = 0; j < 8; j++) {
        int i = base + t * 8 + j;
        if (i < n) row_off[i] = toff + loc[j];
    }
}

// ---------------- scatter: two-sided fill, masked cols front / unmasked cols back ------
__global__ void k_scatter(const int* __restrict__ row, const int* __restrict__ col, int E,
                          const unsigned char* __restrict__ m8,
                          const int* __restrict__ row_off,
                          int* __restrict__ cur_m, int* __restrict__ cur_u,
                          int* __restrict__ col_s) {
    int e = blockIdx.x * 256 + threadIdx.x;
    if (e >= E) return;
    int r = row[e];
    if (m8[r]) return;
    int c = col[e];
    int p;
    if (m8[c]) p = row_off[r] + atomicAdd(&cur_m[r], 1);
    else       p = row_off[r + 1] - 1 - atomicAdd(&cur_u[r], 1);
    col_s[p] = c;
}

// ---------------- compact unmasked rows ----------------
__global__ void k_compact(const unsigned char* __restrict__ m8, int n,
                          int* __restrict__ rows_c, int* __restrict__ cnt) {
    int i = blockIdx.x * 256 + threadIdx.x;
    if (i >= n) return;
    if (!m8[i]) {
        int p = atomicAdd(cnt, 1);
        rows_c[p] = i;
    }
}

// ---------------- init: masked rows of d_out = x ----------------
__global__ void k_init(const float* __restrict__ x, const unsigned char* __restrict__ m8,
                       float* __restrict__ out, int nvec) {
    int i = blockIdx.x * 256 + threadIdx.x;  // float4 index, 32 per node
    if (i >= nvec) return;
    int node = i >> 5;
    if (m8[node]) ((float4*)out)[i] = ((const float4*)x)[i];
}

// ---------------- S_fix[r] = sum over masked cols of dis[c]*x[c]  (fp16 store) --------
__global__ __launch_bounds__(256) void k_sfix(const float* __restrict__ x,
                                              const float* __restrict__ dis,
                                              const int* __restrict__ rows_c,
                                              const int* __restrict__ cnt_p,
                                              const int* __restrict__ row_off,
                                              const int* __restrict__ cur_m,
                                              const int* __restrict__ col_s,
                                              uint2* __restrict__ S) {
    int wid = (blockIdx.x * 256 + threadIdx.x) >> 6;
    int lane = threadIdx.x & 63;
    if (wid >= *cnt_p) return;
    int r = __builtin_amdgcn_readfirstlane(rows_c[wid]);
    int beg = __builtin_amdgcn_readfirstlane(row_off[r]);
    int end = beg + __builtin_amdgcn_readfirstlane(cur_m[r]);

    int s = lane >> 5;     // edge slot 0..1
    int f = lane & 31;     // float4 slot within 512B row
    const float4* xb = (const float4*)x + f;

    float a0 = 0, a1 = 0, a2 = 0, a3 = 0;
    float b0 = 0, b1 = 0, b2 = 0, b3 = 0;
    int e = beg;
    for (; e + 8 <= end; e += 8) {
        int c0 = col_s[e + s],     c1 = col_s[e + 2 + s];
        int c2 = col_s[e + 4 + s], c3 = col_s[e + 6 + s];
        float w0 = dis[c0], w1 = dis[c1], w2 = dis[c2], w3 = dis[c3];
        float4 v0 = xb[(size_t)c0 * 32];
        float4 v1 = xb[(size_t)c1 * 32];
        float4 v2 = xb[(size_t)c2 * 32];
        float4 v3 = xb[(size_t)c3 * 32];
        a0 += w0 * v0.x; a1 += w0 * v0.y; a2 += w0 * v0.z; a3 += w0 * v0.w;
        b0 += w1 * v1.x; b1 += w1 * v1.y; b2 += w1 * v1.z; b3 += w1 * v1.w;
        a0 += w2 * v2.x; a1 += w2 * v2.y; a2 += w2 * v2.z; a3 += w2 * v2.w;
        b0 += w3 * v3.x; b1 += w3 * v3.y; b2 += w3 * v3.z; b3 += w3 * v3.w;
    }
    for (; e + 2 <= end; e += 2) {
        int c = col_s[e + s];
        float w = dis[c];
        float4 v = xb[(size_t)c * 32];
        a0 += w * v.x; a1 += w * v.y; a2 += w * v.z; a3 += w * v.w;
    }
    if (e < end && s == 0) {
        int c = col_s[e];
        float w = dis[c];
        float4 v = xb[(size_t)c * 32];
        a0 += w * v.x; a1 += w * v.y; a2 += w * v.z; a3 += w * v.w;
    }
    a0 += b0; a1 += b1; a2 += b2; a3 += b3;
    a0 += __shfl_xor(a0, 32, 64);
    a1 += __shfl_xor(a1, 32, 64);
    a2 += __shfl_xor(a2, 32, 64);
    a3 += __shfl_xor(a3, 32, 64);
    if (lane < 32) {
        __half2 h0 = __floats2half2_rn(a0, a1);
        __half2 h1 = __floats2half2_rn(a2, a3);
        uint2 o;
        __builtin_memcpy(&o.x, &h0, 4);
        __builtin_memcpy(&o.y, &h1, 4);
        S[(size_t)r * 32 + f] = o;
    }
}

// ---------------- apply: u1 = dis^2 * S_fix (iteration 1, no gather) ----------------
__global__ void k_apply(const uint2* __restrict__ S, const float* __restrict__ dis,
                        const int* __restrict__ rows_c, const int* __restrict__ cnt_p,
                        uint2* __restrict__ uA, int N) {
    int tid = blockIdx.x * 256 + threadIdx.x;   // (compact row, uint2 slot)
    int wid = tid >> 5;
    int f = tid & 31;
    if (wid >= *cnt_p) return;
    int r = rows_c[wid];
    float d = dis[r];
    float s2 = d * d;
    uint2 sv = S[(size_t)r * 32 + f];
    __half2 h0, h1;
    __builtin_memcpy(&h0, &sv.x, 4);
    __builtin_memcpy(&h1, &sv.y, 4);
    float2 v0 = __half22float2(h0);
    float2 v1 = __half22float2(h1);
    h0 = __floats2half2_rn(s2 * v0.x, s2 * v0.y);
    h1 = __floats2half2_rn(s2 * v1.x, s2 * v1.y);
    uint2 o;
    __builtin_memcpy(&o.x, &h0, 4);
    __builtin_memcpy(&o.y, &h1, 4);
    uA[(size_t)r * 32 + f] = o;
}

// ---------------- iteration: gather only unmasked-col edges, acc starts at S_fix -------
// u_new[r] = dis^2 * (S_fix[r] + sum u[c]); final: out[r] = dis * (...) fp32.
template <bool FINAL>
__global__ __launch_bounds__(256) void k_iter(const uint2* __restrict__ src,
                                              void* __restrict__ dst,
                                              const uint2* __restrict__ S,
                                              const int* __restrict__ rows_c,
                                              const int* __restrict__ cnt_p,
                                              const int* __restrict__ row_off,
                                              const int* __restrict__ cur_m,
                                              const int* __restrict__ col_s,
                                              const float* __restrict__ dis) {
    int wid = (blockIdx.x * 256 + threadIdx.x) >> 6;
    int lane = threadIdx.x & 63;
    if (wid >= *cnt_p) return;
    int r = __builtin_amdgcn_readfirstlane(rows_c[wid]);
    int beg = __builtin_amdgcn_readfirstlane(row_off[r] + cur_m[r]);
    int end = __builtin_amdgcn_readfirstlane(row_off[r + 1]);

    int s = lane >> 5;     // edge slot 0..1
    int f = lane & 31;     // uint2 (half4) slot, row stride 32
    const uint2* cb = src + f;

    float a0, a1, a2, a3;
    if (s == 0) {
        uint2 sv = S[(size_t)r * 32 + f];
        __half2 h0, h1;
        __builtin_memcpy(&h0, &sv.x, 4);
        __builtin_memcpy(&h1, &sv.y, 4);
        float2 v0 = __half22float2(h0);
        float2 v1 = __half22float2(h1);
        a0 = v0.x; a1 = v0.y; a2 = v1.x; a3 = v1.y;
    } else {
        a0 = a1 = a2 = a3 = 0.f;
    }
    float b0 = 0.f, b1 = 0.f, b2 = 0.f, b3 = 0.f;

    int e = beg;
    for (; e + 16 <= end; e += 16) {
        int c[8];
#pragma unroll
        for (int j = 0; j < 8; j++) c[j] = col_s[e + 2 * j + s];
        uint2 g[8];
#pragma unroll
        for (int j = 0; j < 8; j++) g[j] = cb[(size_t)c[j] * 32];
#pragma unroll
        for (int j = 0; j < 8; j++) {
            __half2 hlo, hhi;
            __builtin_memcpy(&hlo, &g[j].x, 4);
            __builtin_memcpy(&hhi, &g[j].y, 4);
            float2 vlo = __half22float2(hlo);
            float2 vhi = __half22float2(hhi);
            if (j & 1) { b0 += vlo.x; b1 += vlo.y; b2 += vhi.x; b3 += vhi.y; }
            else       { a0 += vlo.x; a1 += vlo.y; a2 += vhi.x; a3 += vhi.y; }
        }
    }
    for (; e + 2 <= end; e += 2) {
        int c = col_s[e + s];
        uint2 g = cb[(size_t)c * 32];
        __half2 hlo, hhi;
        __builtin_memcpy(&hlo, &g.x, 4);
        __builtin_memcpy(&hhi, &g.y, 4);
        float2 vlo = __half22float2(hlo);
        float2 vhi = __half22float2(hhi);
        a0 += vlo.x; a1 += vlo.y; a2 += vhi.x; a3 += vhi.y;
    }
    if (e < end && s == 0) {
        int c = col_s[e];
        uint2 g = cb[(size_t)c * 32];
        __half2 hlo, hhi;
        __builtin_memcpy(&hlo, &g.x, 4);
        __builtin_memcpy(&hhi, &g.y, 4);
        float2 vlo = __half22float2(hlo);
        float2 vhi = __half22float2(hhi);
        a0 += vlo.x; a1 += vlo.y; a2 += vhi.x; a3 += vhi.y;
    }
    a0 += b0; a1 += b1; a2 += b2; a3 += b3;
    a0 += __shfl_xor(a0, 32, 64);
    a1 += __shfl_xor(a1, 32, 64);
    a2 += __shfl_xor(a2, 32, 64);
    a3 += __shfl_xor(a3, 32, 64);

    if (lane < 32) {
        float d = dis[r];
        if (FINAL) {
            ((float4*)dst)[(size_t)r * 32 + f] = make_float4(d * a0, d * a1, d * a2, d * a3);
        } else {
            float ss = d * d;
            __half2 h0 = __floats2half2_rn(ss * a0, ss * a1);
            __half2 h1 = __floats2half2_rn(ss * a2, ss * a3);
            uint2 o;
            __builtin_memcpy(&o.x, &h0, 4);
            __builtin_memcpy(&o.y, &h1, 4);
            ((uint2*)dst)[(size_t)r * 32 + f] = o;
        }
    }
}

extern "C" void kernel_launch(void* const* d_in, const int* in_sizes, int n_in,
                              void* d_out, int out_size, void* d_ws, size_t ws_size,
                              hipStream_t stream) {
    const float* x = (const float*)d_in[0];
    const int* ei = (const int*)d_in[1];
    const void* mraw = d_in[2];

    const int N = in_sizes[0] / D;     // 100000
    const int E = in_sizes[1] / 2;     // 3200000
    const int* row = ei;
    const int* col = ei + E;

    char* ws = (char*)d_ws;
    size_t off = 0;
    uint2* uA = (uint2*)(ws + off);         off += (size_t)N * D * 2;   // fp16 u buffers
    uint2* uB = (uint2*)(ws + off);         off += (size_t)N * D * 2;
    uint2* S  = (uint2*)(ws + off);         off += (size_t)N * D * 2;   // fp16 S_fix
    int* col_s = (int*)(ws + off);          off += (size_t)E * 4;       // CSR cols (filtered, split)
    int* row_off = (int*)(ws + off);        off += (size_t)(N + 1) * 4;
    int* zblock = (int*)(ws + off);         off += (size_t)(4 * N + 1) * 4; // deg|rdeg|cur_m|cur_u|cnt
    int* deg = zblock;
    int* rdeg = zblock + N;
    int* cur_m = zblock + 2 * N;
    int* cur_u = zblock + 3 * N;
    int* cnt = zblock + 4 * N;
    float* dis = (float*)(ws + off);        off += (size_t)N * 4;
    int* rows_c = (int*)(ws + off);         off += (size_t)N * 4;
    unsigned char* m8 = (unsigned char*)(ws + off); off += (size_t)N;
    off = (off + 255) & ~(size_t)255;
    int* csum = (int*)(ws + off);           off += 256 * 4;
    int* flag = (int*)(ws + off);           off += 4;

    (void)hipMemsetAsync(zblock, 0, (size_t)(4 * N + 1) * 4, stream);

    k_detect<<<1, 256, 0, stream>>>((const unsigned char*)mraw, N, flag);
    k_mask<<<(N + 255) / 256, 256, 0, stream>>>(mraw, flag, m8, N);
    k_deg<<<(E + 255) / 256, 256, 0, stream>>>(row, col, E, m8, deg, rdeg);
    k_dis<<<(N + 255) / 256, 256, 0, stream>>>(deg, dis, N);

    int nch = (N + 2047) / 2048;
    k_scan1<<<nch, 256, 0, stream>>>(rdeg, csum, N);
    k_scan2<<<1, 64, 0, stream>>>(csum, nch, row_off, N);
    k_scan3<<<nch, 256, 0, stream>>>(rdeg, csum, row_off, N);

    k_scatter<<<(E + 255) / 256, 256, 0, stream>>>(row, col, E, m8, row_off, cur_m, cur_u, col_s);
    k_compact<<<(N + 255) / 256, 256, 0, stream>>>(m8, N, rows_c, cnt);

    int nvec = N * (D / 4);
    k_init<<<(nvec + 255) / 256, 256, 0, stream>>>(x, m8, (float*)d_out, nvec);

    int wblocks = (N + 3) / 4;   // one wave per compact row, 4 waves/block (upper bound)
    k_sfix<<<wblocks, 256, 0, stream>>>(x, dis, rows_c, cnt, row_off, cur_m, col_s, S);
    k_apply<<<(N * 32 + 255) / 256, 256, 0, stream>>>(S, dis, rows_c, cnt, uA, N);

    // u1 in uA; 18 fp16 gather iterations (u2..u19), then final fp32 iteration -> d_out
    uint2* src = uA;
    uint2* dst = uB;
    for (int it = 0; it < N_ITER - 2; it++) {
        k_iter<false><<<wblocks, 256, 0, stream>>>(src, dst, S, rows_c, cnt, row_off, cur_m, col_s, dis);
        uint2* t = src; src = dst; dst = t;
    }
    k_iter<true><<<wblocks, 256, 0, stream>>>(src, d_out, S, rows_c, cnt, row_off, cur_m, col_s, dis);
}